// Round 24
// baseline (146.935 us; speedup 1.0000x reference)
//
#include <hip/hip_runtime.h>
#include <stdint.h>

// ProposalLayer: top-6000 select -> bbox regression+clip -> greedy NMS -> 2000 proposals
// B=8, N=261888, all float32.

#define BATCH   8
#define NN      261888
#define PRE_NMS 6000
#define NUM_PROP 2000
#define CAND_CAP 8192
#define EDGE_CAP 16384
#define NTILE   94         // ceil(6000/64)
#define NPAD    6016       // NTILE*64
#define NW32    188
#define NPAIRS  (NTILE*(NTILE+1)/2)   // 4465 tile pairs
#define EWAVES  8                      // waves per k_edges block
#define PGRID   160                    // k_edges blocks per batch (stride survivors)

// workspace layout (bytes)
#define OFF_HIST1  4096
#define OFF_KEY    (OFF_HIST1 + BATCH*4096*4)          // zero covers [0, OFF_KEY)
#define OFF_SBOX   OFF_HIST1
#define OFF_SORTED (OFF_SBOX + BATCH*NPAD*16)          // clear of sbox (R11 lesson)
#define OFF_BOXES  (OFF_SORTED + BATCH*PRE_NMS*4)
#define OFF_EDGES  (OFF_BOXES + BATCH*NPAD*16)
#define OFF_PLIST  (OFF_EDGES + BATCH*EDGE_CAP*4)      // survivor pair list (worst-case cap)
#define WS_NEED    (OFF_PLIST + BATCH*NPAIRS*4)        // ~2.4 MB (ws is ~268 MB)
// sorig (u16) + tile meta live in the old SORTED region
#define OFF_SORIG  OFF_SORTED
#define OFF_TMETA  (OFF_SORTED + 98304)
// binStart/binCur over EDGES region (consumed before k_edges writes edges)
#define OFF_BSTART OFF_EDGES
#define OFF_BCUR   (OFF_EDGES + BATCH*4096*4)

// state u32 indices: [b]=cross bin c, [8+b]=total emitted keys.
#define CNT_EDGE(b)  (320 + (b)*32)
#define CNT_PAIR(b)  (576 + (b)*32)

#define ZERO_U32   (OFF_KEY/4)   // 33792 u32s to zero (state + histogram)

__device__ __forceinline__ uint32_t fkey(float s){
  uint32_t b = __float_as_uint(s);
  return (b & 0x80000000u) ? ~b : (b | 0x80000000u);   // order-preserving float->u32
}

__device__ __forceinline__ int vbin(float s){
  int bin = (int)(s * 4096.0f);
  return bin < 0 ? 0 : (bin > 4095 ? 4095 : bin);
}

// uniform-index 64-bit lane read: src must be wave-uniform (readfirstlane'd).
__device__ __forceinline__ uint64_t readlane64(uint64_t v, int src){
  uint32_t lo = __builtin_amdgcn_readlane((uint32_t)(v & 0xFFFFFFFFull), src);
  uint32_t hi = __builtin_amdgcn_readlane((uint32_t)(v >> 32), src);
  return (uint64_t)lo | ((uint64_t)hi << 32);
}

// wave-aggregated counter reservation: one atomic per wave instead of per lane.
__device__ __forceinline__ uint32_t wave_reserve(bool pred, uint32_t* ctr){
  uint64_t m = __ballot((int)pred);
  if (!m) return 0xFFFFFFFFu;
  int lane = (int)(threadIdx.x & 63u);
  int leader = __ffsll((unsigned long long)m) - 1;
  uint32_t base = 0;
  if (lane == leader) base = atomicAdd(ctr, (uint32_t)__popcll(m));
  base = __shfl(base, leader, 64);
  return base + (uint32_t)__popcll(m & ((1ull << lane) - 1ull));
}

// ---- zero state + histogram ----
__global__ void k_zero(char* ws){
  int i = blockIdx.x*256 + threadIdx.x;
  if (i < ZERO_U32) ((uint32_t*)ws)[i] = 0u;
}

// ---- value histogram (float4: 2 score-pairs per load; .y/.w are the scores) ----
__global__ void k_histv(const float* __restrict__ probs, char* ws){
  __shared__ uint32_t h[4096];
  int b = blockIdx.y;
  for (int t = threadIdx.x; t < 4096; t += 256) h[t] = 0;
  __syncthreads();
  const float4* p4 = (const float4*)probs + (size_t)b * (NN/2);
  int base = blockIdx.x * 1024;
  for (int k = 0; k < 4; ++k){
    int m = base + k*256 + threadIdx.x;
    if (m < NN/2){
      float4 v = p4[m];
      atomicAdd(&h[vbin(v.y)], 1u);
      atomicAdd(&h[vbin(v.w)], 1u);
    }
  }
  __syncthreads();
  uint32_t* gh = (uint32_t*)(ws + OFF_HIST1) + b*4096;
  for (int t = threadIdx.x; t < 4096; t += 256) if (h[t]) atomicAdd(&gh[t], h[t]);
}

// ---- resolve: per-bin global start offsets (suffix-count from top) + cross bin ----
__global__ __launch_bounds__(256) void k_resolvev(char* ws){
  uint32_t* state = (uint32_t*)ws;
  __shared__ uint32_t h[4096];
  __shared__ uint32_t pfx[256];
  int b = blockIdx.x, t = threadIdx.x;
  const uint32_t* gh = (const uint32_t*)(ws + OFF_HIST1) + b*4096;
  for (int i = t; i < 4096; i += 256) h[i] = gh[i];
  __syncthreads();
  uint32_t s = 0;
  for (int k = 0; k < 16; ++k) s += h[t*16 + k];
  pfx[t] = s;
  __syncthreads();
  for (int d = 1; d < 256; d <<= 1){
    uint32_t v = (t >= d) ? pfx[t - d] : 0;
    __syncthreads();
    pfx[t] += v;
    __syncthreads();
  }
  uint32_t above = pfx[255] - pfx[t];
  uint32_t* bstart = (uint32_t*)(ws + OFF_BSTART);
  uint32_t* bcur   = (uint32_t*)(ws + OFF_BCUR);
  uint32_t run = above;
  for (int k = 15; k >= 0; --k){
    int bin = t*16 + k;
    uint32_t cnt = h[bin];
    bstart[bin*8 + b] = run;
    bcur[bin*8 + b] = run;
    if (run < PRE_NMS && run + cnt >= PRE_NMS){
      state[b] = (uint32_t)bin;
      state[8 + b] = run + cnt;
    }
    run += cnt;
  }
}

// ---- compact (float4: 2 elements per iteration) ----
__global__ void k_compactv(const float* __restrict__ probs, char* ws){
  uint32_t* state = (uint32_t*)ws;
  uint64_t* keys  = (uint64_t*)(ws + OFF_KEY);
  uint32_t* bcur  = (uint32_t*)(ws + OFF_BCUR);
  int b = blockIdx.y;
  int c = (int)state[b];
  const float4* p4 = (const float4*)probs + (size_t)b * (NN/2);
  int base = blockIdx.x * 1024;
  for (int k = 0; k < 4; ++k){
    int m = base + k*256 + threadIdx.x;
    if (m < NN/2){
      float4 v = p4[m];
      int bin0 = vbin(v.y);
      if (bin0 >= c){
        uint32_t pos = atomicAdd(&bcur[bin0*8 + b], 1u);
        if (pos < CAND_CAP)
          keys[(size_t)b*CAND_CAP + pos] = ((uint64_t)fkey(v.y) << 32) | (uint32_t)(~(uint32_t)(2*m));
      }
      int bin1 = vbin(v.w);
      if (bin1 >= c){
        uint32_t pos = atomicAdd(&bcur[bin1*8 + b], 1u);
        if (pos < CAND_CAP)
          keys[(size_t)b*CAND_CAP + pos] = ((uint64_t)fkey(v.w) << 32) | (uint32_t)(~(uint32_t)(2*m + 1));
      }
    }
  }
}

// ---- FUSED rank + gather ----
__global__ __launch_bounds__(256) void k_rankgather(const float* __restrict__ boff,
                                                    const float* __restrict__ anc,
                                                    char* ws){
#pragma clang fp contract(off)
  uint32_t* state = (uint32_t*)ws;
  int b = blockIdx.y, t = threadIdx.x;
  uint32_t total = state[8 + b]; if (total > CAND_CAP) total = CAND_CAP;
  uint32_t kidx = blockIdx.x*256 + t;
  if (kidx >= total) return;
  const uint64_t* kb = (const uint64_t*)(ws + OFF_KEY) + (size_t)b * CAND_CAP;
  const uint32_t* bstart = (const uint32_t*)(ws + OFF_BSTART);
  const uint32_t* gh = (const uint32_t*)(ws + OFF_HIST1) + b*4096;
  uint64_t my = kb[kidx];
  float s = __uint_as_float((uint32_t)(my >> 32) & 0x7FFFFFFFu);  // exact inverse of fkey (s>=0)
  int bin = vbin(s);
  uint32_t s0 = bstart[bin*8 + b];
  uint32_t e1 = s0 + gh[bin]; if (e1 > total) e1 = total;
  uint32_t rank = s0;
  for (uint32_t j = s0; j < e1; ++j) rank += (kb[j] > my) ? 1u : 0u;
  if (rank >= PRE_NMS) return;
  uint32_t id = ~(uint32_t)(my & 0xFFFFFFFFull);
  float4* boxes = (float4*)(ws + OFF_BOXES);
  float4 d4 = ((const float4*)boff)[(size_t)b*NN + id];
  float4 a4 = ((const float4*)anc )[(size_t)b*NN + id];
  float d0 = d4.x*0.1f, d1 = d4.y*0.1f, d2 = d4.z*0.2f, d3 = d4.w*0.2f;
  float h = a4.z - a4.x;
  float w = a4.w - a4.y;
  float cy = a4.x + 0.5f*h + d0*h;
  float cx = a4.y + 0.5f*w + d1*w;
  float h2 = h * expf(d2);
  float w2 = w * expf(d3);
  float y1 = cy - 0.5f*h2, x1 = cx - 0.5f*w2;
  float y2 = cy + 0.5f*h2, x2 = cx + 0.5f*w2;
  y1 = fminf(fmaxf(y1, 0.f), 1.f);
  x1 = fminf(fmaxf(x1, 0.f), 1.f);
  y2 = fminf(fmaxf(y2, 0.f), 1.f);
  x2 = fminf(fmaxf(x2, 0.f), 1.f);
  boxes[(size_t)b*NPAD + rank] = make_float4(y1, x1, y2, x2);
}

// ---- spatial counting sort + tile bounds + FUSED pair prune ----
// After computing tmeta (barrier), the same block prunes this batch's 4465
// tile pairs into plist — the separate k_prune node (and its re-read of
// tmeta from a cold kernel) is eliminated. Same decode, test, and emission.
__global__ __launch_bounds__(1024) void k_cellsort(char* ws){
  __shared__ uint32_t hist[256];
  __shared__ uint32_t cur[256];
  __shared__ uint16_t cell[PRE_NMS];
  uint32_t* state = (uint32_t*)ws;
  int b = blockIdx.x, t = threadIdx.x;
  const float4* boxes = (const float4*)(ws + OFF_BOXES) + (size_t)b*NPAD;
  float4* sbox = (float4*)(ws + OFF_SBOX) + (size_t)b*NPAD;
  uint16_t* sorig = (uint16_t*)(ws + OFF_SORIG) + (size_t)b*NPAD;
  float* tmeta = (float*)(ws + OFF_TMETA) + (size_t)b*NTILE*6;
  if (t < 256) hist[t] = 0;
  __syncthreads();
  for (int k = t; k < PRE_NMS; k += 1024){
    float4 bx = boxes[k];
    float cy = 0.5f*(bx.x + bx.z), cx = 0.5f*(bx.y + bx.w);
    int iy = (int)(cy*32.f); iy = iy < 0 ? 0 : (iy > 31 ? 31 : iy);
    int ix = (int)(cx*8.f);  ix = ix < 0 ? 0 : (ix > 7 ? 7 : ix);
    int c = (iy << 3) | ix;
    cell[k] = (uint16_t)c;
    atomicAdd(&hist[c], 1u);
  }
  __syncthreads();
  if (t < 256) cur[t] = hist[t];
  __syncthreads();
  for (int d = 1; d < 256; d <<= 1){
    uint32_t v = 0;
    if (t < 256 && t >= d) v = cur[t - d];
    __syncthreads();
    if (t < 256) cur[t] += v;
    __syncthreads();
  }
  if (t < 256) cur[t] -= hist[t];
  __syncthreads();
  for (int k = t; k < PRE_NMS; k += 1024){
    uint32_t slot = atomicAdd(&cur[cell[k]], 1u);
    sbox[slot] = boxes[k];
    sorig[slot] = (uint16_t)k;
  }
  for (int k = PRE_NMS + t; k < NPAD; k += 1024){
    sbox[k] = make_float4(3.f, 3.f, 3.f, 3.f);
    sorig[k] = 0;
  }
  __syncthreads();
  int wid = t >> 6, lane = t & 63;
  for (int tt = wid; tt < NTILE; tt += 16){
    float4 bx = sbox[tt*64 + lane];
    float cy = 0.5f*(bx.x + bx.z), cx = 0.5f*(bx.y + bx.w);
    float h = bx.z - bx.x, w = bx.w - bx.y;
    float cymin = cy, cymax = cy, cxmin = cx, cxmax = cx, hmax = h, wmax = w;
    for (int d = 32; d >= 1; d >>= 1){
      cymin = fminf(cymin, __shfl_xor(cymin, d));
      cymax = fmaxf(cymax, __shfl_xor(cymax, d));
      cxmin = fminf(cxmin, __shfl_xor(cxmin, d));
      cxmax = fmaxf(cxmax, __shfl_xor(cxmax, d));
      hmax  = fmaxf(hmax,  __shfl_xor(hmax,  d));
      wmax  = fmaxf(wmax,  __shfl_xor(wmax,  d));
    }
    if (lane == 0){
      tmeta[tt*6+0] = cymin; tmeta[tt*6+1] = cymax;
      tmeta[tt*6+2] = cxmin; tmeta[tt*6+3] = cxmax;
      tmeta[tt*6+4] = hmax;  tmeta[tt*6+5] = wmax;
    }
  }
  __syncthreads();                       // tmeta complete for this batch
  // fused pair prune (R19/R23 k_prune body, per-thread over pairs)
  uint32_t* plist = (uint32_t*)(ws + OFF_PLIST);
  for (int p0 = t; p0 < ((NPAIRS + 1023) & ~1023); p0 += 1024){
    bool ok = p0 < NPAIRS;
    int ti = 0, tj = 0;
    if (ok){
      int p = p0;
      while (p >= NTILE - ti){ p -= NTILE - ti; ++ti; }
      tj = ti + p;
      const float* mi = tmeta + ti*6;
      const float* mj = tmeta + tj*6;
      float gapy = fmaxf(fmaxf(mj[0] - mi[1], mi[0] - mj[1]), 0.f);
      float gapx = fmaxf(fmaxf(mj[2] - mi[3], mi[2] - mj[3]), 0.f);
      float by = 0.3015f*fminf(mi[4], mj[4]) + 2e-5f;
      float bx = 0.3015f*fminf(mi[5], mj[5]) + 2e-5f;
      ok = !(gapy >= by || gapx >= bx);
    }
    uint32_t slot = wave_reserve(ok, &state[CNT_PAIR(b)]);
    if (ok) plist[(size_t)b*NPAIRS + slot] = ((uint32_t)ti << 8) | (uint32_t)tj;
  }
}

// ---- sparse edge build over SURVIVOR pairs: 8 waves/block, per-wave LDS slab,
//      grid-stride plist, per-lane jmask. Exact M-test; same edge set. ----
__global__ __launch_bounds__(512) void k_edges(char* ws){
#pragma clang fp contract(off)
  const double M = 0x1.666667p-1;        // 0.7000000178813934326171875
  uint32_t* state = (uint32_t*)ws;
  const float4* sbox = (const float4*)(ws + OFF_SBOX);
  const uint16_t* sorig = (const uint16_t*)(ws + OFF_SORIG);
  const float* tmeta = (const float*)(ws + OFF_TMETA);
  uint32_t* edges = (uint32_t*)(ws + OFF_EDGES);
  __shared__ float4 cb[EWAVES][64];
  __shared__ float  ca[EWAVES][64];
  __shared__ uint16_t co[EWAVES][64];
  int b = blockIdx.y;
  int wid = (int)(threadIdx.x >> 6), t = (int)(threadIdx.x & 63u);
  uint32_t cnt = state[CNT_PAIR(b)]; if (cnt > NPAIRS) cnt = NPAIRS;
  const uint32_t* plist = (const uint32_t*)(ws + OFF_PLIST) + (size_t)b*NPAIRS;
  for (uint32_t p0 = blockIdx.x*EWAVES + wid; p0 < cnt; p0 += PGRID*EWAVES){
    uint32_t pe = plist[p0];
    int ti = (int)(pe >> 8), tj = (int)(pe & 255u);
    const float* mi = tmeta + ((size_t)b*NTILE + ti)*6;
    int j0 = tj*64 + t;
    float4 bj0 = sbox[(size_t)b*NPAD + j0];
    cb[wid][t] = bj0;
    ca[wid][t] = (bj0.z - bj0.x)*(bj0.w - bj0.y);
    co[wid][t] = sorig[(size_t)b*NPAD + j0];
    float cyj = 0.5f*(bj0.x + bj0.z), cxj = 0.5f*(bj0.y + bj0.w);
    float hj = bj0.z - bj0.x, wj = bj0.w - bj0.y;
    float gy = fmaxf(fmaxf(mi[0] - cyj, cyj - mi[1]), 0.f);
    float gx = fmaxf(fmaxf(mi[2] - cxj, cxj - mi[3]), 0.f);
    bool plaus = (gy < 0.3015f*fminf(mi[4], hj) + 2e-5f) &&
                 (gx < 0.3015f*fminf(mi[5], wj) + 2e-5f);
    uint64_t jmask = __ballot((int)plaus);
    __builtin_amdgcn_s_waitcnt(0);        // drain: slab writes visible, prior reads done
    int si = ti*64 + t;
    float4 bi = sbox[(size_t)b*NPAD + si];
    float ai = (bi.z - bi.x)*(bi.w - bi.y);
    uint32_t oi = sorig[(size_t)b*NPAD + si];
    uint64_t vm = (ti < tj) ? ~0ull : ((t == 63) ? 0ull : (~0ull << (t + 1)));
    uint64_t hitmask = 0;
    uint64_t jm = jmask;
    while (jm){
      int jj = __ffsll((unsigned long long)jm) - 1;
      jm &= jm - 1;
      float4 bj = cb[wid][jj];
      float yy1 = fmaxf(bi.x, bj.x);
      float xx1 = fmaxf(bi.y, bj.y);
      float yy2 = fminf(bi.z, bj.z);
      float xx2 = fminf(bi.w, bj.w);
      float ih = fmaxf(yy2 - yy1, 0.f);
      float iw = fmaxf(xx2 - xx1, 0.f);
      float inter = ih * iw;
      float uni = ai + ca[wid][jj] - inter + 1e-9f;
      bool hit = (double)inter >= M * (double)uni;
      hitmask |= hit ? (1ull << jj) : 0ull;
    }
    hitmask &= vm;
    while (__any((int)(hitmask != 0ull))){
      bool pred = hitmask != 0ull;
      int jj = pred ? (__ffsll((unsigned long long)hitmask) - 1) : 0;
      uint32_t slot = wave_reserve(pred, &state[CNT_EDGE(b)]);
      if (pred && slot < EDGE_CAP){
        uint32_t oj = co[wid][jj];
        uint32_t lo = oi < oj ? oi : oj;
        uint32_t hi = oi < oj ? oj : oi;
        edges[(size_t)b*EDGE_CAP + slot] = lo | (hi << 13);
      }
      hitmask &= hitmask - 1;
    }
  }
}

// ---- greedy NMS sweep: window-bucketed edges + prefix-batch selection.
//      Block now 512 threads: bucketing passes halved; serial phase wave 0. ----
__global__ __launch_bounds__(512) void k_scan(char* ws, float* __restrict__ out){
  __shared__ uint32_t ebuf[EDGE_CAP];      // (i&63)<<16 | j
  __shared__ uint32_t wdeg[NTILE + 1];
  __shared__ uint32_t woffs[NTILE + 1];
  __shared__ uint32_t wcur[NTILE];
  __shared__ uint32_t suppr[NW32];
  __shared__ uint32_t adjlo[64];
  __shared__ uint32_t adjhi[64];
  uint32_t* state = (uint32_t*)ws;
  const uint32_t* eb = (const uint32_t*)(ws + OFF_EDGES) + (size_t)blockIdx.x * EDGE_CAP;
  const float4* boxes = (const float4*)(ws + OFF_BOXES);
  int b = blockIdx.x, t = threadIdx.x;

  if (t <= NTILE) wdeg[t] = 0;
  for (int i = t; i < NW32; i += 512) suppr[i] = 0;
  __syncthreads();
  uint32_t E = state[CNT_EDGE(b)]; if (E > EDGE_CAP) E = EDGE_CAP;
  for (uint32_t e = t; e < E; e += 512)
    atomicAdd(&wdeg[(eb[e] & 0x1FFFu) >> 6], 1u);
  __syncthreads();
  if (t <= NTILE) woffs[t] = wdeg[t];
  __syncthreads();
  for (int d = 1; d <= NTILE; d <<= 1){
    uint32_t v = 0;
    if (t <= NTILE && t >= d) v = woffs[t - d];
    __syncthreads();
    if (t <= NTILE) woffs[t] += v;
    __syncthreads();
  }
  if (t <= NTILE){
    uint32_t ex = woffs[t] - wdeg[t];
    woffs[t] = ex;
    if (t < NTILE) wcur[t] = ex;
  }
  __syncthreads();
  for (uint32_t e = t; e < E; e += 512){
    uint32_t ed = eb[e];
    uint32_t ii = ed & 0x1FFFu, jj = ed >> 13;
    uint32_t slot = atomicAdd(&wcur[ii >> 6], 1u);
    ebuf[slot] = ((ii & 63u) << 16) | jj;
  }
  __syncthreads();
  if (t >= 64) return;                     // serial phase: wave 0 only
  int lane = t;
  uint32_t nsel = 0;
  float4 nbox = boxes[(size_t)b*NPAD + lane];       // prefetch window 0
  for (int w = 0; w < NTILE && nsel < NUM_PROP; ++w){
    int base = w*64;
    float4 mybox = nbox;
    if (w + 1 < NTILE) nbox = boxes[(size_t)b*NPAD + base + 64 + lane];  // prefetch next
    adjlo[lane] = 0; adjhi[lane] = 0;
    uint64_t sup = (uint64_t)suppr[2*w] | ((uint64_t)suppr[2*w + 1] << 32);
    uint64_t live = ~sup;
    int valid = PRE_NMS - base;
    if (valid < 64) live &= ((1ull << valid) - 1ull);
    uint32_t r0 = woffs[w], r1 = woffs[w + 1];
    bool anyIn = false;
    for (uint32_t idx = r0 + (uint32_t)lane; idx < r1; idx += 64){
      uint32_t e = ebuf[idx];
      uint32_t il = e >> 16, j = e & 0xFFFFu;
      if (((live >> il) & 1ull) && j < (uint32_t)(base + 64)){
        uint32_t l2 = j - (uint32_t)base;
        if (l2 < 32) atomicOr(&adjlo[il], 1u << l2);
        else         atomicOr(&adjhi[il], 1u << (l2 - 32));
        anyIn = true;
      }
    }
    anyIn = __any((int)anyIn);
    uint64_t sel;
    if (!anyIn){
      uint32_t cnt = __popcll(live);
      uint32_t remn = NUM_PROP - nsel;
      uint32_t take = cnt < remn ? cnt : remn;
      if (live & (1ull << lane)){
        uint32_t r = __popcll(live & ((1ull << lane) - 1ull));
        if (r < take) ((float4*)out)[(size_t)b*NUM_PROP + nsel + r] = mybox;
      }
      nsel += take;
      sel = live;
    } else {
      uint64_t row = (uint64_t)adjlo[lane] | ((uint64_t)adjhi[lane] << 32);
      uint64_t srcmask = __ballot((int)(row != 0ull));
      uint64_t m = live;
      sel = 0;
      while (m && nsel < NUM_PROP){
        uint64_t S = m & srcmask;
        int fS = S ? (__ffsll((unsigned long long)S) - 1) : 64;
        uint64_t below = (fS >= 64) ? ~0ull : ((1ull << fS) - 1ull);
        uint64_t freebits = m & below;
        if (freebits){
          uint32_t cnt = __popcll(freebits);
          uint32_t remn = NUM_PROP - nsel;
          uint32_t take = cnt < remn ? cnt : remn;
          if (freebits & (1ull << lane)){
            uint32_t r = __popcll(freebits & ((1ull << lane) - 1ull));
            if (r < take) ((float4*)out)[(size_t)b*NUM_PROP + nsel + r] = mybox;
          }
          nsel += take;
          sel |= freebits;
          m &= ~freebits;
          if (nsel >= NUM_PROP) break;
        }
        if (fS < 64){
          int fU = __builtin_amdgcn_readfirstlane(fS);
          if (lane == fU) ((float4*)out)[(size_t)b*NUM_PROP + nsel] = mybox;
          sel |= 1ull << fU;
          nsel++;
          m &= ~(1ull << fU);
          if (nsel >= NUM_PROP) break;
          m &= ~readlane64(row, fU);
        }
      }
    }
    if (nsel >= NUM_PROP) break;
    for (uint32_t idx = r0 + (uint32_t)lane; idx < r1; idx += 64){
      uint32_t e = ebuf[idx];
      uint32_t il = e >> 16, j = e & 0xFFFFu;
      if (((sel >> il) & 1ull) && j >= (uint32_t)(base + 64))
        atomicOr(&suppr[j >> 5], 1u << (j & 31));
    }
  }
  for (uint32_t r = nsel + (uint32_t)lane; r < NUM_PROP; r += 64)
    ((float4*)out)[(size_t)b*NUM_PROP + r] = make_float4(0.f, 0.f, 0.f, 0.f);
}

extern "C" void kernel_launch(void* const* d_in, const int* in_sizes, int n_in,
                              void* d_out, int out_size, void* d_ws, size_t ws_size,
                              hipStream_t stream){
  const float* probs = (const float*)d_in[0];
  const float* boff  = (const float*)d_in[1];
  const float* anc   = (const float*)d_in[2];
  char* ws = (char*)d_ws;
  float* out = (float*)d_out;

  k_zero      <<<(ZERO_U32 + 255)/256, 256, 0, stream>>>(ws);
  k_histv     <<<dim3(128, BATCH), 256, 0, stream>>>(probs, ws);
  k_resolvev  <<<BATCH, 256, 0, stream>>>(ws);
  k_compactv  <<<dim3(128, BATCH), 256, 0, stream>>>(probs, ws);
  k_rankgather<<<dim3(26, BATCH), 256, 0, stream>>>(boff, anc, ws);
  k_cellsort  <<<BATCH, 1024, 0, stream>>>(ws);
  k_edges     <<<dim3(PGRID, BATCH), 512, 0, stream>>>(ws);
  k_scan      <<<BATCH, 512, 0, stream>>>(ws, out);
}

// Round 25
// 141.807 us; speedup vs baseline: 1.0362x; 1.0362x over previous
//
#include <hip/hip_runtime.h>
#include <stdint.h>

// ProposalLayer: top-6000 select -> bbox regression+clip -> greedy NMS -> 2000 proposals
// B=8, N=261888, all float32.
// Best-known build (R22, 142.5us): float4 score passes, fused rank+gather,
// cellsort, 8-wave k_edges (closed-form decode + per-lane jmask), k_scan with
// window-bucketed edges + prefix-batch greedy selection.

#define BATCH   8
#define NN      261888
#define PRE_NMS 6000
#define NUM_PROP 2000
#define CAND_CAP 8192
#define EDGE_CAP 16384
#define NTILE   94         // ceil(6000/64)
#define NPAD    6016       // NTILE*64
#define NW32    188
#define NPAIRS  (NTILE*(NTILE+1)/2)   // 4465 tile pairs
#define EWAVES  8                      // pairs (waves) per k_edges block

// workspace layout (bytes)
#define OFF_HIST1  4096
#define OFF_KEY    (OFF_HIST1 + BATCH*4096*4)          // zero covers [0, OFF_KEY)
#define OFF_SBOX   OFF_HIST1
#define OFF_SORTED (OFF_SBOX + BATCH*NPAD*16)          // clear of sbox (R11 lesson)
#define OFF_BOXES  (OFF_SORTED + BATCH*PRE_NMS*4)
#define OFF_EDGES  (OFF_BOXES + BATCH*NPAD*16)
#define WS_NEED    (OFF_EDGES + BATCH*EDGE_CAP*4)      // ~2.26 MB
// sorig (u16) + tile meta live in the old SORTED region
#define OFF_SORIG  OFF_SORTED
#define OFF_TMETA  (OFF_SORTED + 98304)
// binStart/binCur over EDGES region (consumed before k_edges writes edges)
#define OFF_BSTART OFF_EDGES
#define OFF_BCUR   (OFF_EDGES + BATCH*4096*4)

// state u32 indices: [b]=cross bin c, [8+b]=total emitted keys.
#define CNT_EDGE(b)  (320 + (b)*32)

#define ZERO_U32   (OFF_KEY/4)   // 33792 u32s to zero (state + histogram)

__device__ __forceinline__ uint32_t fkey(float s){
  uint32_t b = __float_as_uint(s);
  return (b & 0x80000000u) ? ~b : (b | 0x80000000u);   // order-preserving float->u32
}

__device__ __forceinline__ int vbin(float s){
  int bin = (int)(s * 4096.0f);
  return bin < 0 ? 0 : (bin > 4095 ? 4095 : bin);
}

// uniform-index 64-bit lane read: src must be wave-uniform (readfirstlane'd).
__device__ __forceinline__ uint64_t readlane64(uint64_t v, int src){
  uint32_t lo = __builtin_amdgcn_readlane((uint32_t)(v & 0xFFFFFFFFull), src);
  uint32_t hi = __builtin_amdgcn_readlane((uint32_t)(v >> 32), src);
  return (uint64_t)lo | ((uint64_t)hi << 32);
}

// wave-aggregated counter reservation: one atomic per wave instead of per lane.
__device__ __forceinline__ uint32_t wave_reserve(bool pred, uint32_t* ctr){
  uint64_t m = __ballot((int)pred);
  if (!m) return 0xFFFFFFFFu;
  int lane = (int)(threadIdx.x & 63u);
  int leader = __ffsll((unsigned long long)m) - 1;
  uint32_t base = 0;
  if (lane == leader) base = atomicAdd(ctr, (uint32_t)__popcll(m));
  base = __shfl(base, leader, 64);
  return base + (uint32_t)__popcll(m & ((1ull << lane) - 1ull));
}

// ---- zero state + histogram ----
__global__ void k_zero(char* ws){
  int i = blockIdx.x*256 + threadIdx.x;
  if (i < ZERO_U32) ((uint32_t*)ws)[i] = 0u;
}

// ---- value histogram (float4: 2 score-pairs per load; .y/.w are the scores) ----
__global__ void k_histv(const float* __restrict__ probs, char* ws){
  __shared__ uint32_t h[4096];
  int b = blockIdx.y;
  for (int t = threadIdx.x; t < 4096; t += 256) h[t] = 0;
  __syncthreads();
  const float4* p4 = (const float4*)probs + (size_t)b * (NN/2);
  int base = blockIdx.x * 1024;
  for (int k = 0; k < 4; ++k){
    int m = base + k*256 + threadIdx.x;
    if (m < NN/2){
      float4 v = p4[m];
      atomicAdd(&h[vbin(v.y)], 1u);
      atomicAdd(&h[vbin(v.w)], 1u);
    }
  }
  __syncthreads();
  uint32_t* gh = (uint32_t*)(ws + OFF_HIST1) + b*4096;
  for (int t = threadIdx.x; t < 4096; t += 256) if (h[t]) atomicAdd(&gh[t], h[t]);
}

// ---- resolve: per-bin global start offsets (suffix-count from top) + cross bin ----
__global__ __launch_bounds__(256) void k_resolvev(char* ws){
  uint32_t* state = (uint32_t*)ws;
  __shared__ uint32_t h[4096];
  __shared__ uint32_t pfx[256];
  int b = blockIdx.x, t = threadIdx.x;
  const uint32_t* gh = (const uint32_t*)(ws + OFF_HIST1) + b*4096;
  for (int i = t; i < 4096; i += 256) h[i] = gh[i];
  __syncthreads();
  uint32_t s = 0;
  for (int k = 0; k < 16; ++k) s += h[t*16 + k];
  pfx[t] = s;
  __syncthreads();
  for (int d = 1; d < 256; d <<= 1){
    uint32_t v = (t >= d) ? pfx[t - d] : 0;
    __syncthreads();
    pfx[t] += v;
    __syncthreads();
  }
  uint32_t above = pfx[255] - pfx[t];
  uint32_t* bstart = (uint32_t*)(ws + OFF_BSTART);
  uint32_t* bcur   = (uint32_t*)(ws + OFF_BCUR);
  uint32_t run = above;
  for (int k = 15; k >= 0; --k){
    int bin = t*16 + k;
    uint32_t cnt = h[bin];
    bstart[bin*8 + b] = run;
    bcur[bin*8 + b] = run;
    if (run < PRE_NMS && run + cnt >= PRE_NMS){
      state[b] = (uint32_t)bin;
      state[8 + b] = run + cnt;
    }
    run += cnt;
  }
}

// ---- compact (float4: 2 elements per iteration; same bin test, key packing) ----
__global__ void k_compactv(const float* __restrict__ probs, char* ws){
  uint32_t* state = (uint32_t*)ws;
  uint64_t* keys  = (uint64_t*)(ws + OFF_KEY);
  uint32_t* bcur  = (uint32_t*)(ws + OFF_BCUR);
  int b = blockIdx.y;
  int c = (int)state[b];
  const float4* p4 = (const float4*)probs + (size_t)b * (NN/2);
  int base = blockIdx.x * 1024;
  for (int k = 0; k < 4; ++k){
    int m = base + k*256 + threadIdx.x;
    if (m < NN/2){
      float4 v = p4[m];
      int bin0 = vbin(v.y);
      if (bin0 >= c){
        uint32_t pos = atomicAdd(&bcur[bin0*8 + b], 1u);
        if (pos < CAND_CAP)
          keys[(size_t)b*CAND_CAP + pos] = ((uint64_t)fkey(v.y) << 32) | (uint32_t)(~(uint32_t)(2*m));
      }
      int bin1 = vbin(v.w);
      if (bin1 >= c){
        uint32_t pos = atomicAdd(&bcur[bin1*8 + b], 1u);
        if (pos < CAND_CAP)
          keys[(size_t)b*CAND_CAP + pos] = ((uint64_t)fkey(v.w) << 32) | (uint32_t)(~(uint32_t)(2*m + 1));
      }
    }
  }
}

// ---- FUSED rank + gather ----
__global__ __launch_bounds__(256) void k_rankgather(const float* __restrict__ boff,
                                                    const float* __restrict__ anc,
                                                    char* ws){
#pragma clang fp contract(off)
  uint32_t* state = (uint32_t*)ws;
  int b = blockIdx.y, t = threadIdx.x;
  uint32_t total = state[8 + b]; if (total > CAND_CAP) total = CAND_CAP;
  uint32_t kidx = blockIdx.x*256 + t;
  if (kidx >= total) return;
  const uint64_t* kb = (const uint64_t*)(ws + OFF_KEY) + (size_t)b * CAND_CAP;
  const uint32_t* bstart = (const uint32_t*)(ws + OFF_BSTART);
  const uint32_t* gh = (const uint32_t*)(ws + OFF_HIST1) + b*4096;
  uint64_t my = kb[kidx];
  float s = __uint_as_float((uint32_t)(my >> 32) & 0x7FFFFFFFu);  // exact inverse of fkey (s>=0)
  int bin = vbin(s);
  uint32_t s0 = bstart[bin*8 + b];
  uint32_t e1 = s0 + gh[bin]; if (e1 > total) e1 = total;
  uint32_t rank = s0;
  for (uint32_t j = s0; j < e1; ++j) rank += (kb[j] > my) ? 1u : 0u;
  if (rank >= PRE_NMS) return;
  uint32_t id = ~(uint32_t)(my & 0xFFFFFFFFull);
  float4* boxes = (float4*)(ws + OFF_BOXES);
  float4 d4 = ((const float4*)boff)[(size_t)b*NN + id];
  float4 a4 = ((const float4*)anc )[(size_t)b*NN + id];
  float d0 = d4.x*0.1f, d1 = d4.y*0.1f, d2 = d4.z*0.2f, d3 = d4.w*0.2f;
  float h = a4.z - a4.x;
  float w = a4.w - a4.y;
  float cy = a4.x + 0.5f*h + d0*h;
  float cx = a4.y + 0.5f*w + d1*w;
  float h2 = h * expf(d2);
  float w2 = w * expf(d3);
  float y1 = cy - 0.5f*h2, x1 = cx - 0.5f*w2;
  float y2 = cy + 0.5f*h2, x2 = cx + 0.5f*w2;
  y1 = fminf(fmaxf(y1, 0.f), 1.f);
  x1 = fminf(fmaxf(x1, 0.f), 1.f);
  y2 = fminf(fmaxf(y2, 0.f), 1.f);
  x2 = fminf(fmaxf(x2, 0.f), 1.f);
  boxes[(size_t)b*NPAD + rank] = make_float4(y1, x1, y2, x2);
}

// ---- spatial counting sort into 32x8 cells + per-64-box-tile bounds ----
__global__ __launch_bounds__(1024) void k_cellsort(char* ws){
  __shared__ uint32_t hist[256];
  __shared__ uint32_t cur[256];
  __shared__ uint16_t cell[PRE_NMS];
  int b = blockIdx.x, t = threadIdx.x;
  const float4* boxes = (const float4*)(ws + OFF_BOXES) + (size_t)b*NPAD;
  float4* sbox = (float4*)(ws + OFF_SBOX) + (size_t)b*NPAD;
  uint16_t* sorig = (uint16_t*)(ws + OFF_SORIG) + (size_t)b*NPAD;
  float* tmeta = (float*)(ws + OFF_TMETA) + (size_t)b*NTILE*6;
  if (t < 256) hist[t] = 0;
  __syncthreads();
  for (int k = t; k < PRE_NMS; k += 1024){
    float4 bx = boxes[k];
    float cy = 0.5f*(bx.x + bx.z), cx = 0.5f*(bx.y + bx.w);
    int iy = (int)(cy*32.f); iy = iy < 0 ? 0 : (iy > 31 ? 31 : iy);
    int ix = (int)(cx*8.f);  ix = ix < 0 ? 0 : (ix > 7 ? 7 : ix);
    int c = (iy << 3) | ix;
    cell[k] = (uint16_t)c;
    atomicAdd(&hist[c], 1u);
  }
  __syncthreads();
  if (t < 256) cur[t] = hist[t];
  __syncthreads();
  for (int d = 1; d < 256; d <<= 1){
    uint32_t v = 0;
    if (t < 256 && t >= d) v = cur[t - d];
    __syncthreads();
    if (t < 256) cur[t] += v;
    __syncthreads();
  }
  if (t < 256) cur[t] -= hist[t];
  __syncthreads();
  for (int k = t; k < PRE_NMS; k += 1024){
    uint32_t slot = atomicAdd(&cur[cell[k]], 1u);
    sbox[slot] = boxes[k];
    sorig[slot] = (uint16_t)k;
  }
  for (int k = PRE_NMS + t; k < NPAD; k += 1024){
    sbox[k] = make_float4(3.f, 3.f, 3.f, 3.f);
    sorig[k] = 0;
  }
  __syncthreads();
  int wid = t >> 6, lane = t & 63;
  for (int tt = wid; tt < NTILE; tt += 16){
    float4 bx = sbox[tt*64 + lane];
    float cy = 0.5f*(bx.x + bx.z), cx = 0.5f*(bx.y + bx.w);
    float h = bx.z - bx.x, w = bx.w - bx.y;
    float cymin = cy, cymax = cy, cxmin = cx, cxmax = cx, hmax = h, wmax = w;
    for (int d = 32; d >= 1; d >>= 1){
      cymin = fminf(cymin, __shfl_xor(cymin, d));
      cymax = fmaxf(cymax, __shfl_xor(cymax, d));
      cxmin = fminf(cxmin, __shfl_xor(cxmin, d));
      cxmax = fmaxf(cxmax, __shfl_xor(cxmax, d));
      hmax  = fmaxf(hmax,  __shfl_xor(hmax,  d));
      wmax  = fmaxf(wmax,  __shfl_xor(wmax,  d));
    }
    if (lane == 0){
      tmeta[tt*6+0] = cymin; tmeta[tt*6+1] = cymax;
      tmeta[tt*6+2] = cxmin; tmeta[tt*6+3] = cxmax;
      tmeta[tt*6+4] = hmax;  tmeta[tt*6+5] = wmax;
    }
  }
}

// ---- sparse edge build: 8 pairs/block, closed-form decode, per-lane jmask ----
__global__ __launch_bounds__(512) void k_edges(char* ws){
#pragma clang fp contract(off)
  const double M = 0x1.666667p-1;        // 0.7000000178813934326171875
  uint32_t* state = (uint32_t*)ws;
  const float4* sbox = (const float4*)(ws + OFF_SBOX);
  const uint16_t* sorig = (const uint16_t*)(ws + OFF_SORIG);
  const float* tmeta = (const float*)(ws + OFF_TMETA);
  uint32_t* edges = (uint32_t*)(ws + OFF_EDGES);
  __shared__ float4 cb[EWAVES][64];
  __shared__ float  ca[EWAVES][64];
  __shared__ uint16_t co[EWAVES][64];
  int b = blockIdx.y;
  int wid = (int)(threadIdx.x >> 6), t = (int)(threadIdx.x & 63u);
  int p0 = blockIdx.x*EWAVES + wid;
  if (p0 >= NPAIRS) return;
  float disc = (float)((2*NTILE+1)*(2*NTILE+1) - 8*p0);
  int ti = (int)(((float)(2*NTILE+1) - sqrtf(disc)) * 0.5f);
  if (ti < 0) ti = 0; if (ti > NTILE-1) ti = NTILE-1;
  while (ti+1 <= NTILE-1 && (ti+1)*NTILE - ((ti+1)*ti)/2 <= p0) ++ti;
  while (ti > 0 && ti*NTILE - (ti*(ti-1))/2 > p0) --ti;
  int tj = ti + (p0 - (ti*NTILE - (ti*(ti-1))/2));
  const float* mi = tmeta + ((size_t)b*NTILE + ti)*6;
  const float* mj = tmeta + ((size_t)b*NTILE + tj)*6;
  float gapy = fmaxf(fmaxf(mj[0] - mi[1], mi[0] - mj[1]), 0.f);
  float gapx = fmaxf(fmaxf(mj[2] - mi[3], mi[2] - mj[3]), 0.f);
  float by = 0.3015f*fminf(mi[4], mj[4]) + 2e-5f;
  float bx = 0.3015f*fminf(mi[5], mj[5]) + 2e-5f;
  if (gapy >= by || gapx >= bx) return;               // wave-uniform exit
  int j0 = tj*64 + t;
  float4 bj0 = sbox[(size_t)b*NPAD + j0];
  cb[wid][t] = bj0;
  ca[wid][t] = (bj0.z - bj0.x)*(bj0.w - bj0.y);
  co[wid][t] = sorig[(size_t)b*NPAD + j0];
  {
    float cyj = 0.5f*(bj0.x + bj0.z), cxj = 0.5f*(bj0.y + bj0.w);
    float hj = bj0.z - bj0.x, wj = bj0.w - bj0.y;
    float gy = fmaxf(fmaxf(mi[0] - cyj, cyj - mi[1]), 0.f);
    float gx = fmaxf(fmaxf(mi[2] - cxj, cxj - mi[3]), 0.f);
    bool plaus = (gy < 0.3015f*fminf(mi[4], hj) + 2e-5f) &&
                 (gx < 0.3015f*fminf(mi[5], wj) + 2e-5f);
    uint64_t jmask = __ballot((int)plaus);
    __builtin_amdgcn_s_waitcnt(0);                    // own-wave LDS writes visible
    int si = ti*64 + t;
    float4 bi = sbox[(size_t)b*NPAD + si];
    float ai = (bi.z - bi.x)*(bi.w - bi.y);
    uint32_t oi = sorig[(size_t)b*NPAD + si];
    uint64_t vm = (ti < tj) ? ~0ull : ((t == 63) ? 0ull : (~0ull << (t + 1)));
    uint64_t hitmask = 0;
    uint64_t jm = jmask;
    while (jm){
      int jj = __ffsll((unsigned long long)jm) - 1;
      jm &= jm - 1;
      float4 bj = cb[wid][jj];
      float yy1 = fmaxf(bi.x, bj.x);
      float xx1 = fmaxf(bi.y, bj.y);
      float yy2 = fminf(bi.z, bj.z);
      float xx2 = fminf(bi.w, bj.w);
      float ih = fmaxf(yy2 - yy1, 0.f);
      float iw = fmaxf(xx2 - xx1, 0.f);
      float inter = ih * iw;
      float uni = ai + ca[wid][jj] - inter + 1e-9f;
      bool hit = (double)inter >= M * (double)uni;
      hitmask |= hit ? (1ull << jj) : 0ull;
    }
    hitmask &= vm;
    while (__any((int)(hitmask != 0ull))){
      bool pred = hitmask != 0ull;
      int jj = pred ? (__ffsll((unsigned long long)hitmask) - 1) : 0;
      uint32_t slot = wave_reserve(pred, &state[CNT_EDGE(b)]);
      if (pred && slot < EDGE_CAP){
        uint32_t oj = co[wid][jj];
        uint32_t lo = oi < oj ? oi : oj;
        uint32_t hi = oi < oj ? oj : oi;
        edges[(size_t)b*EDGE_CAP + slot] = lo | (hi << 13);
      }
      hitmask &= hitmask - 1;
    }
  }
}

// ---- greedy NMS sweep: window-bucketed edges + prefix-batch selection ----
__global__ __launch_bounds__(256) void k_scan(char* ws, float* __restrict__ out){
  __shared__ uint32_t ebuf[EDGE_CAP];      // (i&63)<<16 | j
  __shared__ uint32_t wdeg[NTILE + 1];
  __shared__ uint32_t woffs[NTILE + 1];
  __shared__ uint32_t wcur[NTILE];
  __shared__ uint32_t suppr[NW32];
  __shared__ uint32_t adjlo[64];
  __shared__ uint32_t adjhi[64];
  uint32_t* state = (uint32_t*)ws;
  const uint32_t* eb = (const uint32_t*)(ws + OFF_EDGES) + (size_t)blockIdx.x * EDGE_CAP;
  const float4* boxes = (const float4*)(ws + OFF_BOXES);
  int b = blockIdx.x, t = threadIdx.x;

  if (t <= NTILE) wdeg[t] = 0;
  for (int i = t; i < NW32; i += 256) suppr[i] = 0;
  __syncthreads();
  uint32_t E = state[CNT_EDGE(b)]; if (E > EDGE_CAP) E = EDGE_CAP;
  for (uint32_t e = t; e < E; e += 256)
    atomicAdd(&wdeg[(eb[e] & 0x1FFFu) >> 6], 1u);
  __syncthreads();
  if (t <= NTILE) woffs[t] = wdeg[t];
  __syncthreads();
  for (int d = 1; d <= NTILE; d <<= 1){
    uint32_t v = 0;
    if (t <= NTILE && t >= d) v = woffs[t - d];
    __syncthreads();
    if (t <= NTILE) woffs[t] += v;
    __syncthreads();
  }
  if (t <= NTILE){
    uint32_t ex = woffs[t] - wdeg[t];
    woffs[t] = ex;
    if (t < NTILE) wcur[t] = ex;
  }
  __syncthreads();
  for (uint32_t e = t; e < E; e += 256){
    uint32_t ed = eb[e];
    uint32_t ii = ed & 0x1FFFu, jj = ed >> 13;
    uint32_t slot = atomicAdd(&wcur[ii >> 6], 1u);
    ebuf[slot] = ((ii & 63u) << 16) | jj;
  }
  __syncthreads();
  if (t >= 64) return;                     // serial phase: wave 0 only
  int lane = t;
  uint32_t nsel = 0;
  float4 nbox = boxes[(size_t)b*NPAD + lane];       // prefetch window 0
  for (int w = 0; w < NTILE && nsel < NUM_PROP; ++w){
    int base = w*64;
    float4 mybox = nbox;
    if (w + 1 < NTILE) nbox = boxes[(size_t)b*NPAD + base + 64 + lane];  // prefetch next
    adjlo[lane] = 0; adjhi[lane] = 0;
    uint64_t sup = (uint64_t)suppr[2*w] | ((uint64_t)suppr[2*w + 1] << 32);
    uint64_t live = ~sup;
    int valid = PRE_NMS - base;
    if (valid < 64) live &= ((1ull << valid) - 1ull);
    uint32_t r0 = woffs[w], r1 = woffs[w + 1];
    bool anyIn = false;
    for (uint32_t idx = r0 + (uint32_t)lane; idx < r1; idx += 64){
      uint32_t e = ebuf[idx];
      uint32_t il = e >> 16, j = e & 0xFFFFu;
      if (((live >> il) & 1ull) && j < (uint32_t)(base + 64)){
        uint32_t l2 = j - (uint32_t)base;
        if (l2 < 32) atomicOr(&adjlo[il], 1u << l2);
        else         atomicOr(&adjhi[il], 1u << (l2 - 32));
        anyIn = true;
      }
    }
    anyIn = __any((int)anyIn);
    uint64_t sel;
    if (!anyIn){
      uint32_t cnt = __popcll(live);
      uint32_t remn = NUM_PROP - nsel;
      uint32_t take = cnt < remn ? cnt : remn;
      if (live & (1ull << lane)){
        uint32_t r = __popcll(live & ((1ull << lane) - 1ull));
        if (r < take) ((float4*)out)[(size_t)b*NUM_PROP + nsel + r] = mybox;
      }
      nsel += take;
      sel = live;
    } else {
      uint64_t row = (uint64_t)adjlo[lane] | ((uint64_t)adjhi[lane] << 32);
      uint64_t srcmask = __ballot((int)(row != 0ull));
      uint64_t m = live;
      sel = 0;
      while (m && nsel < NUM_PROP){
        uint64_t S = m & srcmask;
        int fS = S ? (__ffsll((unsigned long long)S) - 1) : 64;
        uint64_t below = (fS >= 64) ? ~0ull : ((1ull << fS) - 1ull);
        uint64_t freebits = m & below;
        if (freebits){
          uint32_t cnt = __popcll(freebits);
          uint32_t remn = NUM_PROP - nsel;
          uint32_t take = cnt < remn ? cnt : remn;
          if (freebits & (1ull << lane)){
            uint32_t r = __popcll(freebits & ((1ull << lane) - 1ull));
            if (r < take) ((float4*)out)[(size_t)b*NUM_PROP + nsel + r] = mybox;
          }
          nsel += take;
          sel |= freebits;
          m &= ~freebits;
          if (nsel >= NUM_PROP) break;
        }
        if (fS < 64){
          int fU = __builtin_amdgcn_readfirstlane(fS);
          if (lane == fU) ((float4*)out)[(size_t)b*NUM_PROP + nsel] = mybox;
          sel |= 1ull << fU;
          nsel++;
          m &= ~(1ull << fU);
          if (nsel >= NUM_PROP) break;
          m &= ~readlane64(row, fU);
        }
      }
    }
    if (nsel >= NUM_PROP) break;
    for (uint32_t idx = r0 + (uint32_t)lane; idx < r1; idx += 64){
      uint32_t e = ebuf[idx];
      uint32_t il = e >> 16, j = e & 0xFFFFu;
      if (((sel >> il) & 1ull) && j >= (uint32_t)(base + 64))
        atomicOr(&suppr[j >> 5], 1u << (j & 31));
    }
  }
  for (uint32_t r = nsel + (uint32_t)lane; r < NUM_PROP; r += 64)
    ((float4*)out)[(size_t)b*NUM_PROP + r] = make_float4(0.f, 0.f, 0.f, 0.f);
}

extern "C" void kernel_launch(void* const* d_in, const int* in_sizes, int n_in,
                              void* d_out, int out_size, void* d_ws, size_t ws_size,
                              hipStream_t stream){
  const float* probs = (const float*)d_in[0];
  const float* boff  = (const float*)d_in[1];
  const float* anc   = (const float*)d_in[2];
  char* ws = (char*)d_ws;
  float* out = (float*)d_out;

  k_zero      <<<(ZERO_U32 + 255)/256, 256, 0, stream>>>(ws);
  k_histv     <<<dim3(128, BATCH), 256, 0, stream>>>(probs, ws);
  k_resolvev  <<<BATCH, 256, 0, stream>>>(ws);
  k_compactv  <<<dim3(128, BATCH), 256, 0, stream>>>(probs, ws);
  k_rankgather<<<dim3(26, BATCH), 256, 0, stream>>>(boff, anc, ws);
  k_cellsort  <<<BATCH, 1024, 0, stream>>>(ws);
  k_edges     <<<dim3((NPAIRS + EWAVES - 1)/EWAVES, BATCH), 512, 0, stream>>>(ws);
  k_scan      <<<BATCH, 256, 0, stream>>>(ws, out);
}